// Round 6
// baseline (145.236 us; speedup 1.0000x reference)
//
#include <hip/hip_runtime.h>

typedef unsigned short u16;
typedef __attribute__((ext_vector_type(8))) short short8;
typedef __attribute__((ext_vector_type(4))) float floatx4;
typedef __attribute__((ext_vector_type(4))) unsigned short ushortx4;

#define BATCH 4
#define SEQ   2048
#define DMODEL 1024

__device__ __forceinline__ u16 f2bf(float f) {
  unsigned int u = __builtin_bit_cast(unsigned int, f);
  u = (u + 0x7FFFu + ((u >> 16) & 1u)) >> 16;
  return (u16)u;
}

typedef const __attribute__((address_space(1))) unsigned int as1_u32;
typedef __attribute__((address_space(3))) unsigned int as3_u32;

__device__ __forceinline__ void gload16(const void* gp, void* lp) {
  __builtin_amdgcn_global_load_lds((as1_u32*)gp, (as3_u32*)lp, 16, 0, 0);
}

#define CFENCE asm volatile("" ::: "memory")
#define LGKM0  do { asm volatile("s_waitcnt lgkmcnt(0)" ::: "memory"); \
                    __builtin_amdgcn_sched_barrier(0); } while (0)
#define VMC(n) asm volatile("s_waitcnt vmcnt(" #n ")" ::: "memory")
#define BAR    __builtin_amdgcn_s_barrier()
#define PRIO1  __builtin_amdgcn_s_setprio(1)
#define PRIO0  __builtin_amdgcn_s_setprio(0)

// ---------------------------------------------------------------------------
// Staging: one "unit" = 16KB-per-8-waves half (h) of A or B of one K-tile
// (BK=64); 2 gloads/thread. LDS dest linear (DMA = uniform base + lane*16);
// XOR swizzle applied on the GLOBAL source 16B slot; readers XOR the address.
// ---------------------------------------------------------------------------
template<int NW, int STRIPE>
__device__ __forceinline__ void stage_unit(
    const u16* __restrict__ G, int ld, int org, int kt, int h,
    u16* region, int w, int l)
{
  constexpr int CPS = STRIPE / 16;
  const int lr = l >> 3, s = l & 7;
  #pragma unroll
  for (int i = 0; i < 2; ++i) {
    int c = i * NW + w;
    int R = (c / CPS) * STRIPE + h * (STRIPE / 2) + (c % CPS) * 8;
    const u16* src = G + (size_t)(org + R + lr) * ld + kt * 64 + ((s ^ lr) << 3);
    gload16(src, region + R * 64);
  }
}

template<int REP>
__device__ __forceinline__ short8 rdfrag(const u16* region, int wq, int m, int kh, int l) {
  int r = wq * (REP * 16) + m * 16 + (l & 15);
  int c = kh * 32 + ((l >> 4) << 3);
  return *(const short8*)(region + ((r * 64 + c) ^ ((r & 7) << 3)));
}

// ---------------------------------------------------------------------------
// m201-style 8-phase Bt-form GEMM core (frame = 2 K-tiles, BK=64, 2 dbufs).
// Unit order of first use per tile: A0,B0 (PhA) B1 (PhB) A1 (PhC).
// Steady-state stage placement (1 unit/phase; region freed >=1 phase before):
//  P1: aLo+bLo(t)  MFMA Q00 | stage A1(t+1)
//  P2: bHi(t)      MFMA Q01 | stage A0(t+2)
//  P3: aHi(t)      MFMA Q11 | stage B0(t+2)
//  P4:             MFMA Q10 | stage B1(t+2), vmcnt(6)  -> t+1 fully resident
//  P5-P8: same for t+1, staging A1(t+2), A0(t+3), B0(t+3), B1(t+3), vmcnt(6)
// Tail stages clamp kt to NT-1 (dummy, keeps counters uniform; regions dead).
// ---------------------------------------------------------------------------
template<int WM, int WN, int MREP, int NREP>
__device__ __forceinline__ void gemm_core(
    const u16* __restrict__ A, int lda,
    const u16* __restrict__ B, int ldb,
    int m0, int n0, int NT, u16* lds,
    floatx4 (&acc)[MREP][NREP])
{
  constexpr int NW = WM * WN;
  constexpr int BM = WM * MREP * 16, BN = WN * NREP * 16;
  constexpr int ABUF = BM * 64;
  constexpr int BUFSZ = (BM + BN) * 64;
  constexpr int MH = MREP / 2, NH = NREP / 2;
  constexpr int SA = BM / WM, SB = BN / WN;

  const int tid = threadIdx.x;
  const int w = tid >> 6, l = tid & 63;
  const int wr = w / WN, wc = w % WN;

  u16* const bufp[2] = { lds, lds + BUFSZ };

  // prologue: A0,B0,B1,A1 of t0; A0,B0,B1 of t1  (A1(t1) comes at P1)
  stage_unit<NW, SA>(A, lda, m0, 0, 0, bufp[0], w, l);
  stage_unit<NW, SB>(B, ldb, n0, 0, 0, bufp[0] + ABUF, w, l);
  stage_unit<NW, SB>(B, ldb, n0, 0, 1, bufp[0] + ABUF, w, l);
  stage_unit<NW, SA>(A, lda, m0, 0, 1, bufp[0], w, l);
  stage_unit<NW, SA>(A, lda, m0, 1, 0, bufp[1], w, l);
  stage_unit<NW, SB>(B, ldb, n0, 1, 0, bufp[1] + ABUF, w, l);
  stage_unit<NW, SB>(B, ldb, n0, 1, 1, bufp[1] + ABUF, w, l);
  VMC(6);                      // t0's 4 units resident; t1's 3 in flight
  BAR;
  CFENCE;

  for (int t = 0; t < NT; t += 2) {
    u16* c0 = bufp[t & 1];
    u16* c1 = bufp[(t + 1) & 1];
    const int t2 = (t + 2 < NT) ? t + 2 : NT - 1;
    const int t3 = (t + 3 < NT) ? t + 3 : NT - 1;

    short8 aLo[MH][2], aHi[MH][2], bLo[NH][2], bHi[NH][2];

    // ================= tile t =================
    // ---- P1 ----
    #pragma unroll
    for (int m = 0; m < MH; ++m)
      #pragma unroll
      for (int k = 0; k < 2; ++k) aLo[m][k] = rdfrag<MREP>(c0, wr, m, k, l);
    #pragma unroll
    for (int n = 0; n < NH; ++n)
      #pragma unroll
      for (int k = 0; k < 2; ++k) bLo[n][k] = rdfrag<NREP>(c0 + ABUF, wc, n, k, l);
    stage_unit<NW, SA>(A, lda, m0, t + 1, 1, c1, w, l);          // A1(t+1)
    if constexpr (MH * 2 + NH * 2 >= 12) asm volatile("s_waitcnt lgkmcnt(8)" ::: "memory");
    BAR; LGKM0; PRIO1;
    #pragma unroll
    for (int m = 0; m < MH; ++m)
      #pragma unroll
      for (int n = 0; n < NH; ++n)
        #pragma unroll
        for (int k = 0; k < 2; ++k)
          acc[m][n] = __builtin_amdgcn_mfma_f32_16x16x32_bf16(aLo[m][k], bLo[n][k], acc[m][n], 0, 0, 0);
    PRIO0; BAR; CFENCE;

    // ---- P2 ----
    #pragma unroll
    for (int n = 0; n < NH; ++n)
      #pragma unroll
      for (int k = 0; k < 2; ++k) bHi[n][k] = rdfrag<NREP>(c0 + ABUF, wc, n + NH, k, l);
    stage_unit<NW, SA>(A, lda, m0, t2, 0, c0, w, l);             // A0(t+2)
    BAR; LGKM0; PRIO1;
    #pragma unroll
    for (int m = 0; m < MH; ++m)
      #pragma unroll
      for (int n = 0; n < NH; ++n)
        #pragma unroll
        for (int k = 0; k < 2; ++k)
          acc[m][n + NH] = __builtin_amdgcn_mfma_f32_16x16x32_bf16(aLo[m][k], bHi[n][k], acc[m][n + NH], 0, 0, 0);
    PRIO0; BAR; CFENCE;

    // ---- P3 ----
    #pragma unroll
    for (int m = 0; m < MH; ++m)
      #pragma unroll
      for (int k = 0; k < 2; ++k) aHi[m][k] = rdfrag<MREP>(c0, wr, m + MH, k, l);
    stage_unit<NW, SB>(B, ldb, n0, t2, 0, c0 + ABUF, w, l);      // B0(t+2)
    BAR; LGKM0; PRIO1;
    #pragma unroll
    for (int m = 0; m < MH; ++m)
      #pragma unroll
      for (int n = 0; n < NH; ++n)
        #pragma unroll
        for (int k = 0; k < 2; ++k)
          acc[m + MH][n + NH] = __builtin_amdgcn_mfma_f32_16x16x32_bf16(aHi[m][k], bHi[n][k], acc[m + MH][n + NH], 0, 0, 0);
    PRIO0; BAR; CFENCE;

    // ---- P4 ----
    stage_unit<NW, SB>(B, ldb, n0, t2, 1, c0 + ABUF, w, l);      // B1(t+2)
    VMC(6);                                                      // t+1 resident
    BAR; PRIO1;
    #pragma unroll
    for (int m = 0; m < MH; ++m)
      #pragma unroll
      for (int n = 0; n < NH; ++n)
        #pragma unroll
        for (int k = 0; k < 2; ++k)
          acc[m + MH][n] = __builtin_amdgcn_mfma_f32_16x16x32_bf16(aHi[m][k], bLo[n][k], acc[m + MH][n], 0, 0, 0);
    PRIO0; BAR; CFENCE;

    // ================= tile t+1 =================
    // ---- P5 ----
    #pragma unroll
    for (int m = 0; m < MH; ++m)
      #pragma unroll
      for (int k = 0; k < 2; ++k) aLo[m][k] = rdfrag<MREP>(c1, wr, m, k, l);
    #pragma unroll
    for (int n = 0; n < NH; ++n)
      #pragma unroll
      for (int k = 0; k < 2; ++k) bLo[n][k] = rdfrag<NREP>(c1 + ABUF, wc, n, k, l);
    stage_unit<NW, SA>(A, lda, m0, t2, 1, c0, w, l);             // A1(t+2)
    if constexpr (MH * 2 + NH * 2 >= 12) asm volatile("s_waitcnt lgkmcnt(8)" ::: "memory");
    BAR; LGKM0; PRIO1;
    #pragma unroll
    for (int m = 0; m < MH; ++m)
      #pragma unroll
      for (int n = 0; n < NH; ++n)
        #pragma unroll
        for (int k = 0; k < 2; ++k)
          acc[m][n] = __builtin_amdgcn_mfma_f32_16x16x32_bf16(aLo[m][k], bLo[n][k], acc[m][n], 0, 0, 0);
    PRIO0; BAR; CFENCE;

    // ---- P6 ----
    #pragma unroll
    for (int n = 0; n < NH; ++n)
      #pragma unroll
      for (int k = 0; k < 2; ++k) bHi[n][k] = rdfrag<NREP>(c1 + ABUF, wc, n + NH, k, l);
    stage_unit<NW, SA>(A, lda, m0, t3, 0, c1, w, l);             // A0(t+3)
    BAR; LGKM0; PRIO1;
    #pragma unroll
    for (int m = 0; m < MH; ++m)
      #pragma unroll
      for (int n = 0; n < NH; ++n)
        #pragma unroll
        for (int k = 0; k < 2; ++k)
          acc[m][n + NH] = __builtin_amdgcn_mfma_f32_16x16x32_bf16(aLo[m][k], bHi[n][k], acc[m][n + NH], 0, 0, 0);
    PRIO0; BAR; CFENCE;

    // ---- P7 ----
    #pragma unroll
    for (int m = 0; m < MH; ++m)
      #pragma unroll
      for (int k = 0; k < 2; ++k) aHi[m][k] = rdfrag<MREP>(c1, wr, m + MH, k, l);
    stage_unit<NW, SB>(B, ldb, n0, t3, 0, c1 + ABUF, w, l);      // B0(t+3)
    BAR; LGKM0; PRIO1;
    #pragma unroll
    for (int m = 0; m < MH; ++m)
      #pragma unroll
      for (int n = 0; n < NH; ++n)
        #pragma unroll
        for (int k = 0; k < 2; ++k)
          acc[m + MH][n + NH] = __builtin_amdgcn_mfma_f32_16x16x32_bf16(aHi[m][k], bHi[n][k], acc[m + MH][n + NH], 0, 0, 0);
    PRIO0; BAR; CFENCE;

    // ---- P8 ----
    stage_unit<NW, SB>(B, ldb, n0, t3, 1, c1 + ABUF, w, l);      // B1(t+3)
    VMC(6);                                                      // t+2 resident
    BAR; PRIO1;
    #pragma unroll
    for (int m = 0; m < MH; ++m)
      #pragma unroll
      for (int n = 0; n < NH; ++n)
        #pragma unroll
        for (int k = 0; k < 2; ++k)
          acc[m + MH][n] = __builtin_amdgcn_mfma_f32_16x16x32_bf16(aHi[m][k], bLo[n][k], acc[m + MH][n], 0, 0, 0);
    PRIO0; BAR; CFENCE;
  }
  VMC(0);   // drain tail dummies
}

// ---------------------------------------------------------------------------
// 1) fp32 -> bf16 convert
// ---------------------------------------------------------------------------
__global__ __launch_bounds__(256)
void convert_k(const float* __restrict__ X,
               const float* __restrict__ WQ,
               const float* __restrict__ WK,
               const float* __restrict__ WV,
               u16* __restrict__ Xb, u16* __restrict__ Wb)
{
  const int NX = (BATCH*SEQ*DMODEL) / 4;
  const int NW_ = (DMODEL*DMODEL) / 4;
  const int total = NX + 3*NW_;
  for (int i = blockIdx.x * 256 + threadIdx.x; i < total; i += gridDim.x * 256) {
    const float4* src; u16* dst; int j;
    if (i < NX) { src = (const float4*)X; j = i; dst = Xb; }
    else {
      int t = i - NX; int w = t / NW_; j = t - w * NW_;
      src = (const float4*)(w == 0 ? WQ : (w == 1 ? WK : WV));
      dst = Wb + (size_t)w * (DMODEL*DMODEL);
    }
    float4 v = src[j];
    ushortx4 p = { f2bf(v.x), f2bf(v.y), f2bf(v.z), f2bf(v.w) };
    *(ushortx4*)(dst + (size_t)j * 4) = p;
  }
}

// ---------------------------------------------------------------------------
// 2a) Q,K projection: 256x256 tiles, 8 waves, 256 blocks = 1 full CU round
// ---------------------------------------------------------------------------
__global__ __launch_bounds__(512, 2)
void qk256(const u16* __restrict__ Xb, const u16* __restrict__ Wb,
           u16* __restrict__ Q, u16* __restrict__ K)
{
  __shared__ __align__(16) u16 lds[2 * (256 + 256) * 64];
  const int id = blockIdx.x;
  const int sw = (id & 7) * 32 + (id >> 3);    // 256 % 8 == 0, bijective
  const int z = sw >> 7;
  const int rem = sw & 127;
  const int mt = rem >> 2, nt = rem & 3;
  const int m0 = mt * 256, n0 = nt * 256;

  floatx4 acc[8][4] = {};
  gemm_core<2, 4, 8, 4>(Xb, DMODEL, Wb + (size_t)z * DMODEL * DMODEL, DMODEL,
                        m0, n0, DMODEL / 64, lds, acc);

  const int l = threadIdx.x & 63, w = threadIdx.x >> 6;
  const int wr = w >> 2, wc = w & 3;
  const int row0 = m0 + wr * 128 + ((l >> 4) << 2);
  const int col0 = n0 + wc * 64 + (l & 15);
  u16* O = z ? K : Q;
  #pragma unroll
  for (int m = 0; m < 8; ++m)
    #pragma unroll
    for (int n = 0; n < 4; ++n)
      #pragma unroll
      for (int i = 0; i < 4; ++i)
        O[(size_t)(row0 + m*16 + i) * DMODEL + col0 + n*16] = f2bf(acc[m][n][i]);
}

// ---------------------------------------------------------------------------
// 2b) V projection: 128x128 tiles, 4 waves, 512 blocks (2/CU), transposed out
// ---------------------------------------------------------------------------
__global__ __launch_bounds__(256, 2)
void v128(const u16* __restrict__ Xb, const u16* __restrict__ Wb,
          u16* __restrict__ Vt)
{
  __shared__ __align__(16) u16 lds[2 * (128 + 128) * 64];
  const int id = blockIdx.x;
  const int sw = (id & 7) * 64 + (id >> 3);    // 512 % 8 == 0
  const int mt = sw >> 3, nt = sw & 7;
  const int m0 = mt * 128, n0 = nt * 128;

  floatx4 acc[4][4] = {};
  gemm_core<2, 2, 4, 4>(Xb, DMODEL, Wb + (size_t)2 * DMODEL * DMODEL, DMODEL,
                        m0, n0, DMODEL / 64, lds, acc);

  const int l = threadIdx.x & 63, w = threadIdx.x >> 6;
  const int wr = w >> 1, wc = w & 1;
  const int row0 = m0 + wr * 64 + ((l >> 4) << 2);
  const int col0 = n0 + wc * 64 + (l & 15);
  #pragma unroll
  for (int m = 0; m < 4; ++m) {
    int gm = row0 + m*16;
    int b = gm >> 11, s = gm & (SEQ - 1);
    #pragma unroll
    for (int n = 0; n < 4; ++n) {
      int d = col0 + n*16;
      ushortx4 p = { f2bf(acc[m][n][0]), f2bf(acc[m][n][1]),
                     f2bf(acc[m][n][2]), f2bf(acc[m][n][3]) };
      *(ushortx4*)(Vt + ((size_t)b * DMODEL + d) * SEQ + s) = p;
    }
  }
}

// ---------------------------------------------------------------------------
// 3) scores = Q @ K^T / 32: 128x128 causal tiles (136/batch, 544 blocks)
// ---------------------------------------------------------------------------
__global__ __launch_bounds__(256, 2)
void scores128(const u16* __restrict__ Qb, const u16* __restrict__ Kb,
               float* __restrict__ Sc)
{
  __shared__ __align__(16) u16 lds[2 * (128 + 128) * 64];
  const int id = blockIdx.x;
  const int sw = (id & 7) * 68 + (id >> 3);    // 544 % 8 == 0
  const int b = sw / 136;
  const int t = sw % 136;
  int qt = 0;
  while ((qt + 1) * (qt + 2) / 2 <= t) ++qt;
  const int kt = t - qt * (qt + 1) / 2;
  const int m0 = qt * 128, n0 = kt * 128;

  const u16* Q = Qb + (size_t)b * SEQ * DMODEL;
  const u16* K = Kb + (size_t)b * SEQ * DMODEL;
  floatx4 acc[4][4] = {};
  gemm_core<2, 2, 4, 4>(Q, DMODEL, K, DMODEL, m0, n0, DMODEL / 64, lds, acc);

  float* S = Sc + (size_t)b * SEQ * SEQ;
  const int l = threadIdx.x & 63, w = threadIdx.x >> 6;
  const int wr = w >> 1, wc = w & 1;
  const int row0 = m0 + wr * 64 + ((l >> 4) << 2);
  const int col0 = n0 + wc * 64 + (l & 15);
  #pragma unroll
  for (int m = 0; m < 4; ++m)
    #pragma unroll
    for (int n = 0; n < 4; ++n)
      #pragma unroll
      for (int i = 0; i < 4; ++i)
        S[(size_t)(row0 + m*16 + i) * SEQ + col0 + n*16] = acc[m][n][i] * 0.03125f;
}

// ---------------------------------------------------------------------------
// 4) causal row softmax, in-place bf16 P overlay; zero-fill to 256-boundary
// ---------------------------------------------------------------------------
__global__ __launch_bounds__(256)
void softmax_k(float* __restrict__ Sc)
{
  __shared__ float buf[SEQ];
  __shared__ float red[4];
  const int rg = blockIdx.x;
  const int q = rg & (SEQ - 1);
  float* row = Sc + (size_t)rg * SEQ;
  u16* prow = (u16*)row;
  const int tid = threadIdx.x;
  const int lane = tid & 63, wave = tid >> 6;
  const int n = q + 1;
  const int kpad = ((q >> 8) + 1) << 8;

  float lmax = -3.4e38f;
  for (int k = tid; k < n; k += 256) {
    float v = row[k];
    buf[k] = v;
    lmax = fmaxf(lmax, v);
  }
  #pragma unroll
  for (int off = 32; off >= 1; off >>= 1)
    lmax = fmaxf(lmax, __shfl_xor(lmax, off));
  if (lane == 0) red[wave] = lmax;
  __syncthreads();
  const float rmax = fmaxf(fmaxf(red[0], red[1]), fmaxf(red[2], red[3]));
  __syncthreads();

  float lsum = 0.f;
  for (int k = tid; k < n; k += 256) {
    float e = __expf(buf[k] - rmax);
    buf[k] = e;
    lsum += e;
  }
  #pragma unroll
  for (int off = 32; off >= 1; off >>= 1)
    lsum += __shfl_xor(lsum, off);
  if (lane == 0) red[wave] = lsum;
  __syncthreads();
  const float inv = 1.f / (red[0] + red[1] + red[2] + red[3]);

  for (int k = tid; k < kpad; k += 256) {
    float p = (k < n) ? buf[k] * inv : 0.f;
    prow[k] = f2bf(p);
  }
}

// ---------------------------------------------------------------------------
// 5) O = P @ V: 128x128 tiles, 512 blocks, complement-qt pairing for balance
// ---------------------------------------------------------------------------
__global__ __launch_bounds__(256, 2)
void out128(const float* __restrict__ Sc, const u16* __restrict__ Vt,
            float* __restrict__ Out)
{
  __shared__ __align__(16) u16 lds[2 * (128 + 128) * 64];
  const int id = blockIdx.x;
  const int j = id & 255;
  const int upper = id >> 8;
  const int qt = upper ? (15 - (j & 15)) : (j & 15);
  const int nt = (j >> 4) & 7;
  const int b  = (upper << 1) | (j >> 7);
  const int m0 = qt * 128, n0 = nt * 128;

  const u16* P = (const u16*)(Sc + (size_t)b * SEQ * SEQ);  // lda = 4096 u16
  const u16* V = Vt + (size_t)b * DMODEL * SEQ;             // ldb = 2048
  const int NT = (qt + 1) * 2;

  floatx4 acc[4][4] = {};
  gemm_core<2, 2, 4, 4>(P, 2 * SEQ, V, SEQ, m0, n0, NT, lds, acc);

  float* O = Out + (size_t)b * SEQ * DMODEL;
  const int l = threadIdx.x & 63, w = threadIdx.x >> 6;
  const int wr = w >> 1, wc = w & 1;
  const int row0 = m0 + wr * 64 + ((l >> 4) << 2);
  const int col0 = n0 + wc * 64 + (l & 15);
  #pragma unroll
  for (int m = 0; m < 4; ++m)
    #pragma unroll
    for (int n = 0; n < 4; ++n)
      #pragma unroll
      for (int i = 0; i < 4; ++i)
        O[(size_t)(row0 + m*16 + i) * DMODEL + col0 + n*16] = acc[m][n][i];
}

// ---------------------------------------------------------------------------
extern "C" void kernel_launch(void* const* d_in, const int* in_sizes, int n_in,
                              void* d_out, int out_size, void* d_ws, size_t ws_size,
                              hipStream_t stream)
{
  const float* X  = (const float*)d_in[0];
  const float* WQ = (const float*)d_in[1];
  const float* WK = (const float*)d_in[2];
  const float* WV = (const float*)d_in[3];
  float* Out = (float*)d_out;

  char* ws = (char*)d_ws;
  u16*   Xb = (u16*)(ws);                       // 16,777,216 B
  u16*   Wb = (u16*)(ws + 16777216);            //  6,291,456 B
  u16*   Qb = (u16*)(ws + 23068672);            // 16,777,216 B
  u16*   Kb = (u16*)(ws + 39845888);            // 16,777,216 B
  u16*   Vt = (u16*)(ws + 56623104);            // 16,777,216 B
  float* Sc = (float*)(ws + 73400320);          // 67,108,864 B

  convert_k<<<dim3(2048), dim3(256), 0, stream>>>(X, WQ, WK, WV, Xb, Wb);
  qk256<<<dim3(256), dim3(512), 0, stream>>>(Xb, Wb, Qb, Kb);
  v128<<<dim3(512), dim3(256), 0, stream>>>(Xb, Wb, Vt);
  scores128<<<dim3(544), dim3(256), 0, stream>>>(Qb, Kb, Sc);
  softmax_k<<<dim3(BATCH * SEQ), dim3(256), 0, stream>>>(Sc);
  out128<<<dim3(512), dim3(256), 0, stream>>>(Sc, Vt, Out);
}

// Round 7
// 134.941 us; speedup vs baseline: 1.0763x; 1.0763x over previous
//
#include <hip/hip_runtime.h>

typedef unsigned short u16;
typedef __attribute__((ext_vector_type(8))) short short8;
typedef __attribute__((ext_vector_type(4))) float floatx4;
typedef __attribute__((ext_vector_type(4))) unsigned short ushortx4;

#define BATCH 4
#define SEQ   2048
#define DMODEL 1024

__device__ __forceinline__ u16 f2bf(float f) {
  unsigned int u = __builtin_bit_cast(unsigned int, f);
  u = (u + 0x7FFFu + ((u >> 16) & 1u)) >> 16;
  return (u16)u;
}
__device__ __forceinline__ float bf2f(u16 u) {
  unsigned int v = ((unsigned int)u) << 16;
  return __builtin_bit_cast(float, v);
}

typedef const __attribute__((address_space(1))) unsigned int as1_u32;
typedef __attribute__((address_space(3))) unsigned int as3_u32;

__device__ __forceinline__ void gload16(const void* gp, void* lp) {
  __builtin_amdgcn_global_load_lds((as1_u32*)gp, (as3_u32*)lp, 16, 0, 0);
}

#define CFENCE asm volatile("" ::: "memory")
#define LGKM0  do { asm volatile("s_waitcnt lgkmcnt(0)" ::: "memory"); \
                    __builtin_amdgcn_sched_barrier(0); } while (0)
#define VMC(n) asm volatile("s_waitcnt vmcnt(" #n ")" ::: "memory")
#define BAR    __builtin_amdgcn_s_barrier()
#define PRIO1  __builtin_amdgcn_s_setprio(1)
#define PRIO0  __builtin_amdgcn_s_setprio(0)

// ---------------------------------------------------------------------------
// Staging: one "unit" = half (h) of A or B of one K-tile (BK=64); 2 gloads
// per thread. LDS dest linear (DMA = uniform base + lane*16); XOR swizzle
// applied on the GLOBAL source 16B slot; readers XOR the address identically.
// ---------------------------------------------------------------------------
template<int NW, int STRIPE>
__device__ __forceinline__ void stage_unit(
    const u16* __restrict__ G, int ld, int org, int kt, int h,
    u16* region, int w, int l)
{
  constexpr int CPS = STRIPE / 16;
  const int lr = l >> 3, s = l & 7;
  #pragma unroll
  for (int i = 0; i < 2; ++i) {
    int c = i * NW + w;
    int R = (c / CPS) * STRIPE + h * (STRIPE / 2) + (c % CPS) * 8;
    const u16* src = G + (size_t)(org + R + lr) * ld + kt * 64 + ((s ^ lr) << 3);
    gload16(src, region + R * 64);
  }
}

template<int REP>
__device__ __forceinline__ short8 rdfrag(const u16* region, int wq, int m, int kh, int l) {
  int r = wq * (REP * 16) + m * 16 + (l & 15);
  int c = kh * 32 + ((l >> 4) << 3);
  return *(const short8*)(region + ((r * 64 + c) ^ ((r & 7) << 3)));
}

// ---------------------------------------------------------------------------
// CORE A (R5 3-phase): best measured for 1-block/CU 256x256 (qk256 41.4us).
// ---------------------------------------------------------------------------
template<int WM, int WN, int MREP, int NREP>
__device__ __forceinline__ void gemm_core3(
    const u16* __restrict__ A, int lda,
    const u16* __restrict__ B, int ldb,
    int m0, int n0, int NT, u16* lds,
    floatx4 (&acc)[MREP][NREP])
{
  constexpr int NW = WM * WN;
  constexpr int BM = WM * MREP * 16, BN = WN * NREP * 16;
  constexpr int ABUF = BM * 64;
  constexpr int BUFSZ = (BM + BN) * 64;
  constexpr int MH = MREP / 2, NH = NREP / 2;
  constexpr int SA = BM / WM, SB = BN / WN;

  const int tid = threadIdx.x;
  const int w = tid >> 6, l = tid & 63;
  const int wr = w / WN, wc = w % WN;

  u16* buf0 = lds;
  u16* buf1 = lds + BUFSZ;

  stage_unit<NW, SA>(A, lda, m0, 0, 0, buf0, w, l);
  stage_unit<NW, SB>(B, ldb, n0, 0, 0, buf0 + ABUF, w, l);
  stage_unit<NW, SB>(B, ldb, n0, 0, 1, buf0 + ABUF, w, l);
  stage_unit<NW, SA>(A, lda, m0, 0, 1, buf0, w, l);
  stage_unit<NW, SA>(A, lda, m0, 1, 0, buf1, w, l);
  stage_unit<NW, SB>(B, ldb, n0, 1, 0, buf1 + ABUF, w, l);
  VMC(8);
  BAR;
  CFENCE;

  for (int kt = 0; kt < NT; ++kt) {
    u16* cur = (kt & 1) ? buf1 : buf0;
    u16* oth = (kt & 1) ? buf0 : buf1;
    const int t1 = (kt + 1 < NT) ? kt + 1 : NT - 1;
    const int t2 = (kt + 2 < NT) ? kt + 2 : NT - 1;

    short8 aLo[MH][2], aHi[MH][2], bLo[NH][2], bHi[NH][2];

    // ---- Phase 0 ----
    #pragma unroll
    for (int m = 0; m < MH; ++m)
      #pragma unroll
      for (int k = 0; k < 2; ++k) aLo[m][k] = rdfrag<MREP>(cur, wr, m, k, l);
    #pragma unroll
    for (int n = 0; n < NH; ++n)
      #pragma unroll
      for (int k = 0; k < 2; ++k) bLo[n][k] = rdfrag<NREP>(cur + ABUF, wc, n, k, l);
    stage_unit<NW, SB>(B, ldb, n0, t1, 1, oth + ABUF, w, l);
    stage_unit<NW, SA>(A, lda, m0, t1, 1, oth, w, l);
    VMC(10);
    LGKM0;
    BAR;
    CFENCE;
    PRIO1;
    #pragma unroll
    for (int m = 0; m < MH; ++m)
      #pragma unroll
      for (int n = 0; n < NH; ++n)
        #pragma unroll
        for (int k = 0; k < 2; ++k)
          acc[m][n] = __builtin_amdgcn_mfma_f32_16x16x32_bf16(aLo[m][k], bLo[n][k], acc[m][n], 0, 0, 0);
    PRIO0;

    // ---- Phase 1 ----
    #pragma unroll
    for (int n = 0; n < NH; ++n)
      #pragma unroll
      for (int k = 0; k < 2; ++k) bHi[n][k] = rdfrag<NREP>(cur + ABUF, wc, n + NH, k, l);
    stage_unit<NW, SA>(A, lda, m0, t2, 0, cur, w, l);
    VMC(10);
    LGKM0;
    BAR;
    CFENCE;
    PRIO1;
    #pragma unroll
    for (int m = 0; m < MH; ++m)
      #pragma unroll
      for (int n = 0; n < NH; ++n)
        #pragma unroll
        for (int k = 0; k < 2; ++k)
          acc[m][n + NH] = __builtin_amdgcn_mfma_f32_16x16x32_bf16(aLo[m][k], bHi[n][k], acc[m][n + NH], 0, 0, 0);
    PRIO0;

    // ---- Phase 2 ----
    #pragma unroll
    for (int m = 0; m < MH; ++m)
      #pragma unroll
      for (int k = 0; k < 2; ++k) aHi[m][k] = rdfrag<MREP>(cur, wr, m + MH, k, l);
    stage_unit<NW, SB>(B, ldb, n0, t2, 0, cur + ABUF, w, l);
    VMC(8);
    LGKM0;
    BAR;
    CFENCE;
    PRIO1;
    #pragma unroll
    for (int m = 0; m < MH; ++m)
      #pragma unroll
      for (int n = 0; n < NH; ++n)
        #pragma unroll
        for (int k = 0; k < 2; ++k) {
          acc[m + MH][n + NH] = __builtin_amdgcn_mfma_f32_16x16x32_bf16(aHi[m][k], bHi[n][k], acc[m + MH][n + NH], 0, 0, 0);
          acc[m + MH][n] = __builtin_amdgcn_mfma_f32_16x16x32_bf16(aHi[m][k], bLo[n][k], acc[m + MH][n], 0, 0, 0);
        }
    PRIO0;
  }
  VMC(0);
}

// ---------------------------------------------------------------------------
// CORE B (R6 8-phase frame): best measured for 2-block/CU 128x128 kernels.
// ---------------------------------------------------------------------------
template<int WM, int WN, int MREP, int NREP>
__device__ __forceinline__ void gemm_core8(
    const u16* __restrict__ A, int lda,
    const u16* __restrict__ B, int ldb,
    int m0, int n0, int NT, u16* lds,
    floatx4 (&acc)[MREP][NREP])
{
  constexpr int NW = WM * WN;
  constexpr int BM = WM * MREP * 16, BN = WN * NREP * 16;
  constexpr int ABUF = BM * 64;
  constexpr int BUFSZ = (BM + BN) * 64;
  constexpr int MH = MREP / 2, NH = NREP / 2;
  constexpr int SA = BM / WM, SB = BN / WN;

  const int tid = threadIdx.x;
  const int w = tid >> 6, l = tid & 63;
  const int wr = w / WN, wc = w % WN;

  u16* const bufp[2] = { lds, lds + BUFSZ };

  stage_unit<NW, SA>(A, lda, m0, 0, 0, bufp[0], w, l);
  stage_unit<NW, SB>(B, ldb, n0, 0, 0, bufp[0] + ABUF, w, l);
  stage_unit<NW, SB>(B, ldb, n0, 0, 1, bufp[0] + ABUF, w, l);
  stage_unit<NW, SA>(A, lda, m0, 0, 1, bufp[0], w, l);
  stage_unit<NW, SA>(A, lda, m0, 1, 0, bufp[1], w, l);
  stage_unit<NW, SB>(B, ldb, n0, 1, 0, bufp[1] + ABUF, w, l);
  stage_unit<NW, SB>(B, ldb, n0, 1, 1, bufp[1] + ABUF, w, l);
  VMC(6);
  BAR;
  CFENCE;

  for (int t = 0; t < NT; t += 2) {
    u16* c0 = bufp[t & 1];
    u16* c1 = bufp[(t + 1) & 1];
    const int t2 = (t + 2 < NT) ? t + 2 : NT - 1;
    const int t3 = (t + 3 < NT) ? t + 3 : NT - 1;

    short8 aLo[MH][2], aHi[MH][2], bLo[NH][2], bHi[NH][2];

    // ---- P1 ----
    #pragma unroll
    for (int m = 0; m < MH; ++m)
      #pragma unroll
      for (int k = 0; k < 2; ++k) aLo[m][k] = rdfrag<MREP>(c0, wr, m, k, l);
    #pragma unroll
    for (int n = 0; n < NH; ++n)
      #pragma unroll
      for (int k = 0; k < 2; ++k) bLo[n][k] = rdfrag<NREP>(c0 + ABUF, wc, n, k, l);
    stage_unit<NW, SA>(A, lda, m0, t + 1, 1, c1, w, l);
    if constexpr (MH * 2 + NH * 2 >= 12) asm volatile("s_waitcnt lgkmcnt(8)" ::: "memory");
    BAR; LGKM0; PRIO1;
    #pragma unroll
    for (int m = 0; m < MH; ++m)
      #pragma unroll
      for (int n = 0; n < NH; ++n)
        #pragma unroll
        for (int k = 0; k < 2; ++k)
          acc[m][n] = __builtin_amdgcn_mfma_f32_16x16x32_bf16(aLo[m][k], bLo[n][k], acc[m][n], 0, 0, 0);
    PRIO0; BAR; CFENCE;

    // ---- P2 ----
    #pragma unroll
    for (int n = 0; n < NH; ++n)
      #pragma unroll
      for (int k = 0; k < 2; ++k) bHi[n][k] = rdfrag<NREP>(c0 + ABUF, wc, n + NH, k, l);
    stage_unit<NW, SA>(A, lda, m0, t2, 0, c0, w, l);
    BAR; LGKM0; PRIO1;
    #pragma unroll
    for (int m = 0; m < MH; ++m)
      #pragma unroll
      for (int n = 0; n < NH; ++n)
        #pragma unroll
        for (int k = 0; k < 2; ++k)
          acc[m][n + NH] = __builtin_amdgcn_mfma_f32_16x16x32_bf16(aLo[m][k], bHi[n][k], acc[m][n + NH], 0, 0, 0);
    PRIO0; BAR; CFENCE;

    // ---- P3 ----
    #pragma unroll
    for (int m = 0; m < MH; ++m)
      #pragma unroll
      for (int k = 0; k < 2; ++k) aHi[m][k] = rdfrag<MREP>(c0, wr, m + MH, k, l);
    stage_unit<NW, SB>(B, ldb, n0, t2, 0, c0 + ABUF, w, l);
    BAR; LGKM0; PRIO1;
    #pragma unroll
    for (int m = 0; m < MH; ++m)
      #pragma unroll
      for (int n = 0; n < NH; ++n)
        #pragma unroll
        for (int k = 0; k < 2; ++k)
          acc[m + MH][n + NH] = __builtin_amdgcn_mfma_f32_16x16x32_bf16(aHi[m][k], bHi[n][k], acc[m + MH][n + NH], 0, 0, 0);
    PRIO0; BAR; CFENCE;

    // ---- P4 ----
    stage_unit<NW, SB>(B, ldb, n0, t2, 1, c0 + ABUF, w, l);
    VMC(6);
    BAR; PRIO1;
    #pragma unroll
    for (int m = 0; m < MH; ++m)
      #pragma unroll
      for (int n = 0; n < NH; ++n)
        #pragma unroll
        for (int k = 0; k < 2; ++k)
          acc[m + MH][n] = __builtin_amdgcn_mfma_f32_16x16x32_bf16(aHi[m][k], bLo[n][k], acc[m + MH][n], 0, 0, 0);
    PRIO0; BAR; CFENCE;

    // ---- P5 ----
    #pragma unroll
    for (int m = 0; m < MH; ++m)
      #pragma unroll
      for (int k = 0; k < 2; ++k) aLo[m][k] = rdfrag<MREP>(c1, wr, m, k, l);
    #pragma unroll
    for (int n = 0; n < NH; ++n)
      #pragma unroll
      for (int k = 0; k < 2; ++k) bLo[n][k] = rdfrag<NREP>(c1 + ABUF, wc, n, k, l);
    stage_unit<NW, SA>(A, lda, m0, t2, 1, c0, w, l);
    if constexpr (MH * 2 + NH * 2 >= 12) asm volatile("s_waitcnt lgkmcnt(8)" ::: "memory");
    BAR; LGKM0; PRIO1;
    #pragma unroll
    for (int m = 0; m < MH; ++m)
      #pragma unroll
      for (int n = 0; n < NH; ++n)
        #pragma unroll
        for (int k = 0; k < 2; ++k)
          acc[m][n] = __builtin_amdgcn_mfma_f32_16x16x32_bf16(aLo[m][k], bLo[n][k], acc[m][n], 0, 0, 0);
    PRIO0; BAR; CFENCE;

    // ---- P6 ----
    #pragma unroll
    for (int n = 0; n < NH; ++n)
      #pragma unroll
      for (int k = 0; k < 2; ++k) bHi[n][k] = rdfrag<NREP>(c1 + ABUF, wc, n + NH, k, l);
    stage_unit<NW, SA>(A, lda, m0, t3, 0, c1, w, l);
    BAR; LGKM0; PRIO1;
    #pragma unroll
    for (int m = 0; m < MH; ++m)
      #pragma unroll
      for (int n = 0; n < NH; ++n)
        #pragma unroll
        for (int k = 0; k < 2; ++k)
          acc[m][n + NH] = __builtin_amdgcn_mfma_f32_16x16x32_bf16(aLo[m][k], bHi[n][k], acc[m][n + NH], 0, 0, 0);
    PRIO0; BAR; CFENCE;

    // ---- P7 ----
    #pragma unroll
    for (int m = 0; m < MH; ++m)
      #pragma unroll
      for (int k = 0; k < 2; ++k) aHi[m][k] = rdfrag<MREP>(c1, wr, m + MH, k, l);
    stage_unit<NW, SB>(B, ldb, n0, t3, 0, c1 + ABUF, w, l);
    BAR; LGKM0; PRIO1;
    #pragma unroll
    for (int m = 0; m < MH; ++m)
      #pragma unroll
      for (int n = 0; n < NH; ++n)
        #pragma unroll
        for (int k = 0; k < 2; ++k)
          acc[m + MH][n + NH] = __builtin_amdgcn_mfma_f32_16x16x32_bf16(aHi[m][k], bHi[n][k], acc[m + MH][n + NH], 0, 0, 0);
    PRIO0; BAR; CFENCE;

    // ---- P8 ----
    stage_unit<NW, SB>(B, ldb, n0, t3, 1, c1 + ABUF, w, l);
    VMC(6);
    BAR; PRIO1;
    #pragma unroll
    for (int m = 0; m < MH; ++m)
      #pragma unroll
      for (int n = 0; n < NH; ++n)
        #pragma unroll
        for (int k = 0; k < 2; ++k)
          acc[m + MH][n] = __builtin_amdgcn_mfma_f32_16x16x32_bf16(aHi[m][k], bLo[n][k], acc[m + MH][n], 0, 0, 0);
    PRIO0; BAR; CFENCE;
  }
  VMC(0);
}

// ---------------------------------------------------------------------------
// 1) fp32 -> bf16 convert
// ---------------------------------------------------------------------------
__global__ __launch_bounds__(256)
void convert_k(const float* __restrict__ X,
               const float* __restrict__ WQ,
               const float* __restrict__ WK,
               const float* __restrict__ WV,
               u16* __restrict__ Xb, u16* __restrict__ Wb)
{
  const int NX = (BATCH*SEQ*DMODEL) / 4;
  const int NW_ = (DMODEL*DMODEL) / 4;
  const int total = NX + 3*NW_;
  for (int i = blockIdx.x * 256 + threadIdx.x; i < total; i += gridDim.x * 256) {
    const float4* src; u16* dst; int j;
    if (i < NX) { src = (const float4*)X; j = i; dst = Xb; }
    else {
      int t = i - NX; int w = t / NW_; j = t - w * NW_;
      src = (const float4*)(w == 0 ? WQ : (w == 1 ? WK : WV));
      dst = Wb + (size_t)w * (DMODEL*DMODEL);
    }
    float4 v = src[j];
    ushortx4 p = { f2bf(v.x), f2bf(v.y), f2bf(v.z), f2bf(v.w) };
    *(ushortx4*)(dst + (size_t)j * 4) = p;
  }
}

// ---------------------------------------------------------------------------
// 2) Q,K projection: 256x256 tiles, 8 waves, 256 blocks, CORE A
// ---------------------------------------------------------------------------
__global__ __launch_bounds__(512, 2)
void qk256(const u16* __restrict__ Xb, const u16* __restrict__ Wb,
           u16* __restrict__ Q, u16* __restrict__ K)
{
  __shared__ __align__(16) u16 lds[2 * (256 + 256) * 64];
  const int id = blockIdx.x;
  const int sw = (id & 7) * 32 + (id >> 3);
  const int z = sw >> 7;
  const int rem = sw & 127;
  const int mt = rem >> 2, nt = rem & 3;
  const int m0 = mt * 256, n0 = nt * 256;

  floatx4 acc[8][4] = {};
  gemm_core3<2, 4, 8, 4>(Xb, DMODEL, Wb + (size_t)z * DMODEL * DMODEL, DMODEL,
                         m0, n0, DMODEL / 64, lds, acc);

  const int l = threadIdx.x & 63, w = threadIdx.x >> 6;
  const int wr = w >> 2, wc = w & 3;
  const int row0 = m0 + wr * 128 + ((l >> 4) << 2);
  const int col0 = n0 + wc * 64 + (l & 15);
  u16* O = z ? K : Q;
  #pragma unroll
  for (int m = 0; m < 8; ++m)
    #pragma unroll
    for (int n = 0; n < 4; ++n)
      #pragma unroll
      for (int i = 0; i < 4; ++i)
        O[(size_t)(row0 + m*16 + i) * DMODEL + col0 + n*16] = f2bf(acc[m][n][i]);
}

// ---------------------------------------------------------------------------
// 3) Merged scores (544 blocks) + V projection (512 blocks): 128x128, CORE B.
//    scores = Q @ K^T / 32 written as BF16 into Sc[b*2048+q][2048].
// ---------------------------------------------------------------------------
__global__ __launch_bounds__(256, 2)
void sv128(const u16* __restrict__ Xb, const u16* __restrict__ Wb,
           const u16* __restrict__ Qb, const u16* __restrict__ Kb,
           u16* __restrict__ Sc, u16* __restrict__ Vt)
{
  __shared__ __align__(16) u16 lds[2 * (128 + 128) * 64];
  const int id = blockIdx.x;
  const int sw = (id & 7) * 132 + (id >> 3);   // 1056 % 8 == 0, bijective

  const u16 *A, *B;
  int m0, n0, b = 0;
  bool is_s;
  if (sw < 544) {
    is_s = true;
    b = sw / 136;
    const int t = sw % 136;
    int qt = 0;
    while ((qt + 1) * (qt + 2) / 2 <= t) ++qt;
    const int kt = t - qt * (qt + 1) / 2;
    m0 = qt * 128; n0 = kt * 128;
    A = Qb + (size_t)b * SEQ * DMODEL;
    B = Kb + (size_t)b * SEQ * DMODEL;
  } else {
    is_s = false;
    const int s = sw - 544;
    m0 = (s >> 3) * 128; n0 = (s & 7) * 128;
    A = Xb;
    B = Wb + (size_t)2 * DMODEL * DMODEL;
  }

  floatx4 acc[4][4] = {};
  gemm_core8<2, 2, 4, 4>(A, DMODEL, B, DMODEL, m0, n0, DMODEL / 64, lds, acc);

  const int l = threadIdx.x & 63, w = threadIdx.x >> 6;
  const int wr = w >> 1, wc = w & 1;
  const int row0 = m0 + wr * 64 + ((l >> 4) << 2);
  const int col0 = n0 + wc * 64 + (l & 15);

  if (is_s) {
    u16* S = Sc + (size_t)b * SEQ * SEQ;
    #pragma unroll
    for (int m = 0; m < 4; ++m)
      #pragma unroll
      for (int n = 0; n < 4; ++n)
        #pragma unroll
        for (int i = 0; i < 4; ++i)
          S[(size_t)(row0 + m*16 + i) * SEQ + col0 + n*16] = f2bf(acc[m][n][i] * 0.03125f);
  } else {
    #pragma unroll
    for (int m = 0; m < 4; ++m) {
      int gm = row0 + m*16;
      int bb = gm >> 11, s2 = gm & (SEQ - 1);
      #pragma unroll
      for (int n = 0; n < 4; ++n) {
        int d = col0 + n*16;
        ushortx4 p = { f2bf(acc[m][n][0]), f2bf(acc[m][n][1]),
                       f2bf(acc[m][n][2]), f2bf(acc[m][n][3]) };
        *(ushortx4*)(Vt + ((size_t)bb * DMODEL + d) * SEQ + s2) = p;
      }
    }
  }
}

// ---------------------------------------------------------------------------
// 4) Single-pass register softmax on bf16 rows: one short8 load + one store
//    per thread; zero-fill up to the 128-tile causal boundary.
// ---------------------------------------------------------------------------
__global__ __launch_bounds__(256)
void softmax1p(u16* __restrict__ Sc)
{
  __shared__ float red[4];
  const int rg = blockIdx.x;
  const int q = rg & (SEQ - 1);
  u16* row = Sc + (size_t)rg * SEQ;
  const int t = threadIdx.x;
  const int lane = t & 63, wave = t >> 6;
  const int n = q + 1;
  const int kpad = ((q >> 7) + 1) << 7;
  const int k0 = t * 8;

  short8 v8 = *(const short8*)(row + k0);
  float f[8];
  float lmax = -3.4e38f;
  #pragma unroll
  for (int j = 0; j < 8; ++j) {
    f[j] = bf2f((u16)v8[j]);
    if (k0 + j < n) lmax = fmaxf(lmax, f[j]);
  }
  #pragma unroll
  for (int off = 32; off >= 1; off >>= 1)
    lmax = fmaxf(lmax, __shfl_xor(lmax, off));
  if (lane == 0) red[wave] = lmax;
  __syncthreads();
  const float rmax = fmaxf(fmaxf(red[0], red[1]), fmaxf(red[2], red[3]));
  __syncthreads();

  float lsum = 0.f;
  #pragma unroll
  for (int j = 0; j < 8; ++j) {
    float e = (k0 + j < n) ? __expf(f[j] - rmax) : 0.f;
    f[j] = e;
    lsum += e;
  }
  #pragma unroll
  for (int off = 32; off >= 1; off >>= 1)
    lsum += __shfl_xor(lsum, off);
  if (lane == 0) red[wave] = lsum;
  __syncthreads();
  const float inv = 1.f / (red[0] + red[1] + red[2] + red[3]);

  if (k0 < kpad) {
    short8 o;
    #pragma unroll
    for (int j = 0; j < 8; ++j) o[j] = (short)f2bf(f[j] * inv);
    *(short8*)(row + k0) = o;
  }
}

// ---------------------------------------------------------------------------
// 5) O = P @ V: 128x128, CORE B; P bf16 (lda 2048); complement-qt pairing.
// ---------------------------------------------------------------------------
__global__ __launch_bounds__(256, 2)
void out128(const u16* __restrict__ Sc, const u16* __restrict__ Vt,
            float* __restrict__ Out)
{
  __shared__ __align__(16) u16 lds[2 * (128 + 128) * 64];
  const int id = blockIdx.x;
  const int j = id & 255;
  const int upper = id >> 8;
  const int qt = upper ? (15 - (j & 15)) : (j & 15);
  const int nt = (j >> 4) & 7;
  const int b  = (upper << 1) | (j >> 7);
  const int m0 = qt * 128, n0 = nt * 128;

  const u16* P = Sc + (size_t)b * SEQ * SEQ;   // lda = 2048 u16
  const u16* V = Vt + (size_t)b * DMODEL * SEQ;
  const int NT = (qt + 1) * 2;

  floatx4 acc[4][4] = {};
  gemm_core8<2, 2, 4, 4>(P, SEQ, V, SEQ, m0, n0, NT, lds, acc);

  float* O = Out + (size_t)b * SEQ * DMODEL;
  const int l = threadIdx.x & 63, w = threadIdx.x >> 6;
  const int wr = w >> 1, wc = w & 1;
  const int row0 = m0 + wr * 64 + ((l >> 4) << 2);
  const int col0 = n0 + wc * 64 + (l & 15);
  #pragma unroll
  for (int m = 0; m < 4; ++m)
    #pragma unroll
    for (int n = 0; n < 4; ++n)
      #pragma unroll
      for (int i = 0; i < 4; ++i)
        O[(size_t)(row0 + m*16 + i) * DMODEL + col0 + n*16] = acc[m][n][i];
}

// ---------------------------------------------------------------------------
extern "C" void kernel_launch(void* const* d_in, const int* in_sizes, int n_in,
                              void* d_out, int out_size, void* d_ws, size_t ws_size,
                              hipStream_t stream)
{
  const float* X  = (const float*)d_in[0];
  const float* WQ = (const float*)d_in[1];
  const float* WK = (const float*)d_in[2];
  const float* WV = (const float*)d_in[3];
  float* Out = (float*)d_out;

  char* ws = (char*)d_ws;
  u16*   Xb = (u16*)(ws);                       // 16,777,216 B
  u16*   Wb = (u16*)(ws + 16777216);            //  6,291,456 B
  u16*   Qb = (u16*)(ws + 23068672);            // 16,777,216 B
  u16*   Kb = (u16*)(ws + 39845888);            // 16,777,216 B
  u16*   Vt = (u16*)(ws + 56623104);            // 16,777,216 B
  u16*   Sc = (u16*)(ws + 73400320);            // 33,554,432 B (bf16 scores/P)

  convert_k<<<dim3(2048), dim3(256), 0, stream>>>(X, WQ, WK, WV, Xb, Wb);
  qk256<<<dim3(256), dim3(512), 0, stream>>>(Xb, Wb, Qb, Kb);
  sv128<<<dim3(1056), dim3(256), 0, stream>>>(Xb, Wb, Qb, Kb, Sc, Vt);
  softmax1p<<<dim3(BATCH * SEQ), dim3(256), 0, stream>>>(Sc);
  out128<<<dim3(512), dim3(256), 0, stream>>>(Sc, Vt, Out);
}